// Round 1
// baseline (1313.231 us; speedup 1.0000x reference)
//
#include <hip/hip_runtime.h>
#include <stdint.h>

typedef __bf16 bf16x8 __attribute__((ext_vector_type(8)));
typedef float f32x4 __attribute__((ext_vector_type(4)));

#define S_LEN 8192
#define BATCH 4
#define DMODEL 512
#define NHEAD 8
#define DHEAD 64
#define MROWS (BATCH * S_LEN)              // 32768
#define OUT0_ELEMS (MROWS * DMODEL)        // 16777216
#define KV_ELEMS (BATCH * NHEAD * DHEAD * DHEAD)  // 131072
#define Z_ELEMS (BATCH * NHEAD * DHEAD)    // 2048

__device__ __forceinline__ uint16_t f2bf(float f) {
    uint32_t u = __float_as_uint(f);
    u = (u + 0x7fffu + ((u >> 16) & 1u)) >> 16;   // RNE
    return (uint16_t)u;
}
__device__ __forceinline__ float bf2f(uint16_t h) {
    return __uint_as_float(((uint32_t)h) << 16);
}

// ---------------- weights fp32 -> bf16 (all four at once) ----------------
__global__ void wconv_kernel(const float* __restrict__ w0, const float* __restrict__ w1,
                             const float* __restrict__ w2, const float* __restrict__ w3,
                             uint16_t* __restrict__ dst) {
    const float* src = (blockIdx.y == 0) ? w0 : (blockIdx.y == 1) ? w1
                       : (blockIdx.y == 2) ? w2 : w3;
    uint16_t* d = dst + (size_t)blockIdx.y * (DMODEL * DMODEL);
    int i = (blockIdx.x * 256 + threadIdx.x) * 4;
    float4 v = *(const float4*)(src + i);
    ushort4 o;
    o.x = f2bf(v.x); o.y = f2bf(v.y); o.z = f2bf(v.z); o.w = f2bf(v.w);
    *(ushort4*)(d + i) = o;
}

// ---------------- generic GEMM: C[m][n] = act(sum_k A[m][k]*W[n][k] + bias[n]) ----
// A: [32768][512] (fp32 or bf16), W: [512][512] bf16 row-major (torch Linear weight),
// Block: 256 thr = 4 waves. Tile M=32 x N=512(full), BK=32.
// Packed-fragment LDS layout: [frag_group][lane][8 bf16] -> all MFMA ds_reads are
// lane-contiguous b128 bursts (conflict-free, no padding needed).
template<bool A_F32, bool ELU1, bool OUT_F32>
__global__ __launch_bounds__(256, 3)
void gemm_kernel(const void* __restrict__ Ap, const uint16_t* __restrict__ Wb,
                 const float* __restrict__ bias, void* __restrict__ Cp)
{
    __shared__ uint16_t sA[1024];    // 2 mi-groups * 64 lanes * 8
    __shared__ uint16_t sB[16384];   // 32 ni-groups * 64 lanes * 8
    const int tid = threadIdx.x;
    const int lane = tid & 63;
    const int w = tid >> 6;
    const int quad = lane >> 4;
    const int l15 = lane & 15;
    const int m_blk = blockIdx.x * 32;

    f32x4 acc[2][8];
#pragma unroll
    for (int mi = 0; mi < 2; ++mi)
#pragma unroll
        for (int ni = 0; ni < 8; ++ni) acc[mi][ni] = (f32x4){0.f, 0.f, 0.f, 0.f};

    // A staging map: thread -> (row 0..31, 4 k-elems)
    const int ar = tid >> 3;
    const int ac = (tid & 7) * 4;
    const int a_dst = (((ar >> 4) * 4 + (ac >> 3)) * 16 + (ar & 15)) * 8 + (ac & 7);

    for (int kk = 0; kk < 16; ++kk) {
        const int k0 = kk * 32;
        // prefetch (issue global loads before the barrier)
        ushort4 apack;
        if (A_F32) {
            float4 av = *(const float4*)((const float*)Ap + (size_t)(m_blk + ar) * 512 + k0 + ac);
            apack.x = f2bf(av.x); apack.y = f2bf(av.y);
            apack.z = f2bf(av.z); apack.w = f2bf(av.w);
        } else {
            apack = *(const ushort4*)((const uint16_t*)Ap + (size_t)(m_blk + ar) * 512 + k0 + ac);
        }
        uint4 bpack[2][4];
#pragma unroll
        for (int rr = 0; rr < 2; ++rr) {
            const int n = rr * 256 + tid;
#pragma unroll
            for (int c8 = 0; c8 < 4; ++c8)
                bpack[rr][c8] = *(const uint4*)(Wb + (size_t)n * 512 + k0 + c8 * 8);
        }
        __syncthreads();   // previous iteration's ds_reads done
        *(ushort4*)(sA + a_dst) = apack;
#pragma unroll
        for (int rr = 0; rr < 2; ++rr) {
            const int n = rr * 256 + tid;
            const int nbase = (n >> 4) * 64 + (n & 15);
#pragma unroll
            for (int c8 = 0; c8 < 4; ++c8)
                *(uint4*)(sB + (nbase + c8 * 16) * 8) = bpack[rr][c8];
        }
        __syncthreads();
        bf16x8 afr[2];
#pragma unroll
        for (int mi = 0; mi < 2; ++mi)
            afr[mi] = *(const bf16x8*)(sA + (mi * 64 + lane) * 8);
#pragma unroll
        for (int ni = 0; ni < 8; ++ni) {
            bf16x8 bfr = *(const bf16x8*)(sB + ((w * 8 + ni) * 64 + lane) * 8);
            acc[0][ni] = __builtin_amdgcn_mfma_f32_16x16x32_bf16(afr[0], bfr, acc[0][ni], 0, 0, 0);
            acc[1][ni] = __builtin_amdgcn_mfma_f32_16x16x32_bf16(afr[1], bfr, acc[1][ni], 0, 0, 0);
        }
    }

    // epilogue: C/D layout col=lane&15, row=quad*4+r
#pragma unroll
    for (int mi = 0; mi < 2; ++mi)
#pragma unroll
        for (int ni = 0; ni < 8; ++ni) {
            const int col = w * 128 + ni * 16 + l15;
            const float bs = bias[col];
#pragma unroll
            for (int r = 0; r < 4; ++r) {
                const int row = m_blk + mi * 16 + quad * 4 + r;
                float val = acc[mi][ni][r] + bs;
                if (ELU1) val = (val > 0.f) ? (val + 1.f) : __expf(val);  // elu(x)+1
                if (OUT_F32)
                    ((float*)Cp)[(size_t)row * 512 + col] = val;
                else
                    ((uint16_t*)Cp)[(size_t)row * 512 + col] = f2bf(val);
            }
        }
}

// ---------------- kv state: kv[b,h,d,m] = sum_s K[s,d]*V[s,m]; z[b,h,d] = sum_s K[s,d]
// grid (32 bh, 32 s-splits), 256 thr. thread: so=t&1 (s-parity, shfl-reduced),
// d=(t>>1)&63, mh=t>>7 (m-half of 32). fp32 accumulate, atomicAdd into d_out.
__global__ __launch_bounds__(256)
void kv_kernel(const uint16_t* __restrict__ Kb, const uint16_t* __restrict__ Vb,
               float* __restrict__ kvz)
{
    __shared__ float sKf[8][64];
    __shared__ float sVf[8][64];
    const int tid = threadIdx.x;
    const int bh = blockIdx.x;
    const int b = bh >> 3, h = bh & 7;
    const int so = tid & 1;
    const int d = (tid >> 1) & 63;
    const int mh = tid >> 7;
    const int m0 = mh * 32;
    const size_t rowbase = (size_t)(b * S_LEN) * DMODEL + h * DHEAD;
    const int s0 = blockIdx.y * 256;

    f32x4 acc8[8];
#pragma unroll
    for (int q8 = 0; q8 < 8; ++q8) acc8[q8] = (f32x4){0.f, 0.f, 0.f, 0.f};
    float zacc = 0.f;

    const int sr = tid >> 5;
    const int sc = (tid * 2) & 63;

    for (int it = 0; it < 32; ++it) {
        const size_t g = rowbase + (size_t)(s0 + it * 8 + sr) * DMODEL + sc;
        uint32_t kr = *(const uint32_t*)(Kb + g);
        uint32_t vr = *(const uint32_t*)(Vb + g);
        __syncthreads();
        sKf[sr][sc]     = bf2f((uint16_t)(kr & 0xffff));
        sKf[sr][sc + 1] = bf2f((uint16_t)(kr >> 16));
        sVf[sr][sc]     = bf2f((uint16_t)(vr & 0xffff));
        sVf[sr][sc + 1] = bf2f((uint16_t)(vr >> 16));
        __syncthreads();
#pragma unroll
        for (int r2 = 0; r2 < 4; ++r2) {
            const int r = r2 * 2 + so;
            const float kd = sKf[r][d];
            if (mh == 0) zacc += kd;
            const f32x4* vrp = (const f32x4*)(&sVf[r][m0]);
#pragma unroll
            for (int q8 = 0; q8 < 8; ++q8)
                acc8[q8] += kd * vrp[q8];
        }
    }
    float* kvp = kvz + ((size_t)bh * 64 + d) * 64 + m0;
#pragma unroll
    for (int q8 = 0; q8 < 8; ++q8)
#pragma unroll
        for (int c = 0; c < 4; ++c) {
            float val = acc8[q8][c];
            val += __shfl_xor(val, 1, 64);
            if (so == 0) atomicAdd(kvp + q8 * 4 + c, val);
        }
    zacc += __shfl_xor(zacc, 1, 64);
    if (so == 0 && mh == 0) atomicAdd(kvz + KV_ELEMS + bh * 64 + d, zacc);
}

// ---------------- attention: y = (Q @ kv) / (Q . z + eps), per (b,h) ------------
// kv augmented with z as column 64 -> one MFMA pass yields num AND den.
// grid (64 s-blocks of 128 rows, 32 bh), 256 thr = 4 waves (32 rows each).
__global__ __launch_bounds__(256, 4)
void attn_kernel(const uint16_t* __restrict__ Qb, const float* __restrict__ kvz,
                 uint16_t* __restrict__ Yb)
{
    __shared__ uint16_t sB[5120];   // 5 ni * 2 kk * 64 lanes * 8
    const int bh = blockIdx.y;
    const int b = bh >> 3, h = bh & 7;
    const float* kv = kvz + (size_t)bh * (DHEAD * DHEAD);
    const float* z  = kvz + KV_ELEMS + (size_t)bh * DHEAD;
    const int tid = threadIdx.x;
    for (int e = tid; e < 80 * 64; e += 256) {
        const int n = e >> 6, d = e & 63;
        float val = (n < 64) ? kv[d * 64 + n] : ((n == 64) ? z[d] : 0.f);
        const int dst = ((((n >> 4) * 2 + (d >> 5)) * 4 + ((d >> 3) & 3)) * 16 + (n & 15)) * 8 + (d & 7);
        sB[dst] = f2bf(val);
    }
    __syncthreads();
    const int lane = tid & 63, w = tid >> 6, quad = lane >> 4, l15 = lane & 15;
    f32x4 acc[2][5];
#pragma unroll
    for (int mi = 0; mi < 2; ++mi)
#pragma unroll
        for (int ni = 0; ni < 5; ++ni) acc[mi][ni] = (f32x4){0.f, 0.f, 0.f, 0.f};
    const int row0 = blockIdx.x * 128 + w * 32;
#pragma unroll
    for (int kk = 0; kk < 2; ++kk) {
        bf16x8 afr[2];
#pragma unroll
        for (int mi = 0; mi < 2; ++mi) {
            const size_t ga = (size_t)(b * S_LEN + row0 + mi * 16 + l15) * DMODEL
                              + h * DHEAD + kk * 32 + quad * 8;
            afr[mi] = *(const bf16x8*)(Qb + ga);
        }
#pragma unroll
        for (int ni = 0; ni < 5; ++ni) {
            bf16x8 bfr = *(const bf16x8*)(sB + ((ni * 2 + kk) * 64 + lane) * 8);
            acc[0][ni] = __builtin_amdgcn_mfma_f32_16x16x32_bf16(afr[0], bfr, acc[0][ni], 0, 0, 0);
            acc[1][ni] = __builtin_amdgcn_mfma_f32_16x16x32_bf16(afr[1], bfr, acc[1][ni], 0, 0, 0);
        }
    }
#pragma unroll
    for (int mi = 0; mi < 2; ++mi) {
        float rden[4];
#pragma unroll
        for (int r = 0; r < 4; ++r) {
            const float den = __shfl(acc[mi][4][r], lane & 48, 64);  // col 64 lives in lane l15==0
            rden[r] = 1.0f / (den + 1e-6f);
        }
#pragma unroll
        for (int ni = 0; ni < 4; ++ni) {
            const int col = h * DHEAD + ni * 16 + l15;
#pragma unroll
            for (int r = 0; r < 4; ++r) {
                const int row = row0 + mi * 16 + quad * 4 + r;
                Yb[(size_t)(b * S_LEN + row) * DMODEL + col] = f2bf(acc[mi][ni][r] * rden[r]);
            }
        }
    }
}

extern "C" void kernel_launch(void* const* d_in, const int* in_sizes, int n_in,
                              void* d_out, int out_size, void* d_ws, size_t ws_size,
                              hipStream_t stream)
{
    const float* q  = (const float*)d_in[0];
    const float* k  = (const float*)d_in[1];
    const float* v  = (const float*)d_in[2];
    const float* Wq = (const float*)d_in[3];
    const float* bq = (const float*)d_in[4];
    const float* Wk = (const float*)d_in[5];
    const float* bk = (const float*)d_in[6];
    const float* Wv = (const float*)d_in[7];
    const float* bv = (const float*)d_in[8];
    const float* Wo = (const float*)d_in[9];
    const float* bo = (const float*)d_in[10];

    uint16_t* Qb = (uint16_t*)d_ws;          // bf16 [32768][512]
    uint16_t* Kb = Qb + OUT0_ELEMS;
    uint16_t* Vb = Kb + OUT0_ELEMS;
    uint16_t* Wb = Vb + OUT0_ELEMS;          // 4 x [512][512] bf16
    uint16_t* Yb = Kb;                       // K dead after kv_kernel -> reuse

    float* out0 = (float*)d_out;
    float* kvz  = out0 + OUT0_ELEMS;         // kv (131072) then z (2048)

    hipMemsetAsync(kvz, 0, (KV_ELEMS + Z_ELEMS) * sizeof(float), stream);
    wconv_kernel<<<dim3(256, 4), 256, 0, stream>>>(Wq, Wk, Wv, Wo, Wb);
    gemm_kernel<true, true,  false><<<dim3(1024), 256, 0, stream>>>(q, Wb,               bq, Qb);
    gemm_kernel<true, true,  false><<<dim3(1024), 256, 0, stream>>>(k, Wb + 262144,      bk, Kb);
    gemm_kernel<true, false, false><<<dim3(1024), 256, 0, stream>>>(v, Wb + 2 * 262144,  bv, Vb);
    kv_kernel<<<dim3(32, 32), 256, 0, stream>>>(Kb, Vb, kvz);
    attn_kernel<<<dim3(64, 32), 256, 0, stream>>>(Qb, kvz, Yb);
    gemm_kernel<false, false, true><<<dim3(1024), 256, 0, stream>>>(Yb, Wb + 3 * 262144, bo, out0);
}

// Round 2
// 586.192 us; speedup vs baseline: 2.2403x; 2.2403x over previous
//
#include <hip/hip_runtime.h>
#include <hip/hip_bf16.h>
#include <stdint.h>

typedef __bf16 bf16x8 __attribute__((ext_vector_type(8)));
typedef float f32x4 __attribute__((ext_vector_type(4)));

#define S_LEN 8192
#define BATCH 4
#define DMODEL 512
#define NHEAD 8
#define DHEAD 64
#define MROWS (BATCH * S_LEN)              // 32768
#define OUT0_ELEMS (MROWS * DMODEL)        // 16777216
#define KV_ELEMS (BATCH * NHEAD * DHEAD * DHEAD)  // 131072
#define Z_ELEMS (BATCH * NHEAD * DHEAD)    // 2048

__device__ __forceinline__ uint16_t f2bf(float f) {
    uint32_t u = __float_as_uint(f);
    u = (u + 0x7fffu + ((u >> 16) & 1u)) >> 16;   // RNE
    return (uint16_t)u;
}
__device__ __forceinline__ uint32_t pack2(float a, float b) {
    // packed RNE f32->bf16x2
    union { __hip_bfloat162 h; uint32_t u; } cv;
    cv.h = __float22bfloat162_rn(make_float2(a, b));
    return cv.u;
}
__device__ __forceinline__ void gload_lds16(const void* g, void* l) {
    __builtin_amdgcn_global_load_lds(
        (const __attribute__((address_space(1))) void*)g,
        (__attribute__((address_space(3))) void*)l, 16, 0, 0);
}

// ---------------- weights fp32 -> bf16 (all four at once) ----------------
__global__ void wconv_kernel(const float* __restrict__ w0, const float* __restrict__ w1,
                             const float* __restrict__ w2, const float* __restrict__ w3,
                             uint16_t* __restrict__ dst) {
    const float* src = (blockIdx.y == 0) ? w0 : (blockIdx.y == 1) ? w1
                       : (blockIdx.y == 2) ? w2 : w3;
    uint16_t* d = dst + (size_t)blockIdx.y * (DMODEL * DMODEL);
    int i = (blockIdx.x * 256 + threadIdx.x) * 4;
    float4 v = *(const float4*)(src + i);
    uint2 o;
    o.x = pack2(v.x, v.y);
    o.y = pack2(v.z, v.w);
    *(uint2*)(d + i) = o;
}

// ---------------- GEMM: C[m][n] = act(sum_k A[m][k]*W[n][k] + bias[n]) ----------
// m97 structure: 128x128 tile, BK=32, 4 waves each 64x64 (4x4 of 16x16x32 MFMA).
// Packed-fragment LDS: slot (g*64+lane)*8 holds X[g*16 + (lane&15)][k0 + (lane>>4)*8 + j]
// -> ds_read_b128 fragment loads are lane-contiguous; global_load_lds width=16 staging.
template<bool A_F32, bool ELU1, bool OUT_F32>
__global__ __launch_bounds__(256, 3)
void gemm_kernel(const void* __restrict__ Ap, const uint16_t* __restrict__ Wb,
                 const float* __restrict__ bias, void* __restrict__ Cp)
{
    __shared__ uint4 smem4[1024];            // 16 KB (k-loop: sA 8K + sB 8K; epilogue: scratch)
    uint16_t* sA = (uint16_t*)smem4;
    uint16_t* sB = (uint16_t*)(smem4 + 512);
    const int tid = threadIdx.x;
    const int lane = tid & 63, w = tid >> 6;
    const int quad = lane >> 4, l15 = lane & 15;
    const int m_blk = blockIdx.y * 128, n_blk = blockIdx.x * 128;

    f32x4 acc[4][4];
#pragma unroll
    for (int mi = 0; mi < 4; ++mi)
#pragma unroll
        for (int ni = 0; ni < 4; ++ni) acc[mi][ni] = (f32x4){0.f, 0.f, 0.f, 0.f};

    const int ar = tid >> 1;      // A fp32 staging: row 0..127
    const int ah = tid & 1;       // k-half (16 cols)
    const int g0 = w * 2;         // this wave's two LDS staging groups

    for (int kk = 0; kk < 16; ++kk) {
        const int k0 = kk * 32;
        uint4 p0, p1;
        if (A_F32) {
            const float* arow = (const float*)Ap + (size_t)(m_blk + ar) * 512 + k0 + ah * 16;
            float4 a0 = *(const float4*)(arow);
            float4 a1 = *(const float4*)(arow + 4);
            float4 a2 = *(const float4*)(arow + 8);
            float4 a3 = *(const float4*)(arow + 12);
            p0 = make_uint4(pack2(a0.x, a0.y), pack2(a0.z, a0.w),
                            pack2(a1.x, a1.y), pack2(a1.z, a1.w));
            p1 = make_uint4(pack2(a2.x, a2.y), pack2(a2.z, a2.w),
                            pack2(a3.x, a3.y), pack2(a3.z, a3.w));
        }
        __syncthreads();   // previous iteration's fragment reads complete
        gload_lds16(Wb + (size_t)(n_blk + g0 * 16 + l15) * 512 + k0 + quad * 8,
                    sB + g0 * 512);
        gload_lds16(Wb + (size_t)(n_blk + (g0 + 1) * 16 + l15) * 512 + k0 + quad * 8,
                    sB + (g0 + 1) * 512);
        if (A_F32) {
            uint16_t* base = sA + (((ar >> 4) * 4 + ah * 2) * 16 + (ar & 15)) * 8;
            *(uint4*)base = p0;
            *(uint4*)(base + 128) = p1;   // next quad group: +16 slots * 8
        } else {
            const uint16_t* Ab = (const uint16_t*)Ap;
            gload_lds16(Ab + (size_t)(m_blk + g0 * 16 + l15) * 512 + k0 + quad * 8,
                        sA + g0 * 512);
            gload_lds16(Ab + (size_t)(m_blk + (g0 + 1) * 16 + l15) * 512 + k0 + quad * 8,
                        sA + (g0 + 1) * 512);
        }
        __syncthreads();   // drains vmcnt (load_lds) + lgkm (ds_writes)
        bf16x8 afr[4], bfr[4];
#pragma unroll
        for (int mi = 0; mi < 4; ++mi)
            afr[mi] = *(const bf16x8*)(sA + (((w & 1) * 4 + mi) * 64 + lane) * 8);
#pragma unroll
        for (int ni = 0; ni < 4; ++ni)
            bfr[ni] = *(const bf16x8*)(sB + (((w >> 1) * 4 + ni) * 64 + lane) * 8);
#pragma unroll
        for (int mi = 0; mi < 4; ++mi)
#pragma unroll
            for (int ni = 0; ni < 4; ++ni)
                acc[mi][ni] = __builtin_amdgcn_mfma_f32_16x16x32_bf16(
                    afr[mi], bfr[ni], acc[mi][ni], 0, 0, 0);
    }
    __syncthreads();       // k-loop LDS dead; reuse as epilogue scratch

    const int mw = (w & 1) * 64, nw = (w >> 1) * 64;
    float bias4[4];
#pragma unroll
    for (int ni = 0; ni < 4; ++ni) bias4[ni] = bias[n_blk + nw + ni * 16 + l15];

    if (OUT_F32) {
        float* t = (float*)(smem4 + w * 256);            // 4 KB per wave
        float* C = (float*)Cp;
#pragma unroll
        for (int mi = 0; mi < 4; ++mi) {
#pragma unroll
            for (int ni = 0; ni < 4; ++ni)
#pragma unroll
                for (int r = 0; r < 4; ++r) {
                    float val = acc[mi][ni][r] + bias4[ni];
                    if (ELU1) val = (val > 0.f) ? (val + 1.f) : __expf(val);
                    t[(quad * 4 + r) * 64 + ni * 16 + l15] = val;
                }
#pragma unroll
            for (int c = 0; c < 4; ++c) {
                const int idx = c * 64 + lane;
                const int row = idx >> 4, colc = (idx & 15) * 4;
                float4 vv = *(const float4*)(t + row * 64 + colc);
                *(float4*)(C + (size_t)(m_blk + mw + mi * 16 + row) * 512
                             + n_blk + nw + colc) = vv;
            }
        }
    } else {
        uint16_t* t = (uint16_t*)(smem4 + w * 128);      // 2 KB per wave
        uint16_t* C = (uint16_t*)Cp;
#pragma unroll
        for (int mi = 0; mi < 4; ++mi) {
#pragma unroll
            for (int ni = 0; ni < 4; ++ni)
#pragma unroll
                for (int r = 0; r < 4; ++r) {
                    float val = acc[mi][ni][r] + bias4[ni];
                    if (ELU1) val = (val > 0.f) ? (val + 1.f) : __expf(val);
                    t[(quad * 4 + r) * 64 + ni * 16 + l15] = f2bf(val);
                }
#pragma unroll
            for (int c = 0; c < 2; ++c) {
                const int idx = c * 64 + lane;
                const int row = idx >> 3, colc = (idx & 7) * 8;
                uint4 vv = *(const uint4*)(t + row * 64 + colc);
                *(uint4*)(C + (size_t)(m_blk + mw + mi * 16 + row) * 512
                            + n_blk + nw + colc) = vv;
            }
        }
    }
}

// ---------------- kv state: kv[b,h,d,m] = sum_s K[s,d]*V[s,m]; z[d] = sum_s K[s,d]
// grid (32 bh, 16 s-splits), 256 thr. thread: d=tid&63, mgrp=tid>>6 (wave-uniform!)
// -> V LDS reads are all-lane broadcast (conflict-free), K reads 2-way (free).
__global__ __launch_bounds__(256)
void kv_kernel(const uint16_t* __restrict__ Kb, const uint16_t* __restrict__ Vb,
               float* __restrict__ kvz)
{
    __shared__ float sK[64][68];   // +4 pad: staging writes spread across banks
    __shared__ float sV[64][68];
    const int tid = threadIdx.x;
    const int bh = blockIdx.x, b = bh >> 3, h = bh & 7;
    const int d = tid & 63, mg = tid >> 6, m0 = mg * 16;
    const int srow = tid >> 2, seg = (tid & 3) * 16;
    const int s0 = blockIdx.y * 512;

    f32x4 acc[4];
#pragma unroll
    for (int c = 0; c < 4; ++c) acc[c] = (f32x4){0.f, 0.f, 0.f, 0.f};
    float zacc = 0.f;

    for (int t8 = 0; t8 < 8; ++t8) {
        const size_t g = ((size_t)(b * S_LEN + s0 + t8 * 64 + srow)) * 512 + h * 64 + seg;
        uint4 kp0 = *(const uint4*)(Kb + g);
        uint4 kp1 = *(const uint4*)(Kb + g + 8);
        uint4 vp0 = *(const uint4*)(Vb + g);
        uint4 vp1 = *(const uint4*)(Vb + g + 8);
        __syncthreads();
        {
            float* pk = &sK[srow][seg];
            float* pv = &sV[srow][seg];
            *(float4*)(pk)     = (float4){__uint_as_float(kp0.x << 16), __uint_as_float(kp0.x & 0xffff0000u),
                                          __uint_as_float(kp0.y << 16), __uint_as_float(kp0.y & 0xffff0000u)};
            *(float4*)(pk + 4) = (float4){__uint_as_float(kp0.z << 16), __uint_as_float(kp0.z & 0xffff0000u),
                                          __uint_as_float(kp0.w << 16), __uint_as_float(kp0.w & 0xffff0000u)};
            *(float4*)(pk + 8) = (float4){__uint_as_float(kp1.x << 16), __uint_as_float(kp1.x & 0xffff0000u),
                                          __uint_as_float(kp1.y << 16), __uint_as_float(kp1.y & 0xffff0000u)};
            *(float4*)(pk + 12)= (float4){__uint_as_float(kp1.z << 16), __uint_as_float(kp1.z & 0xffff0000u),
                                          __uint_as_float(kp1.w << 16), __uint_as_float(kp1.w & 0xffff0000u)};
            *(float4*)(pv)     = (float4){__uint_as_float(vp0.x << 16), __uint_as_float(vp0.x & 0xffff0000u),
                                          __uint_as_float(vp0.y << 16), __uint_as_float(vp0.y & 0xffff0000u)};
            *(float4*)(pv + 4) = (float4){__uint_as_float(vp0.z << 16), __uint_as_float(vp0.z & 0xffff0000u),
                                          __uint_as_float(vp0.w << 16), __uint_as_float(vp0.w & 0xffff0000u)};
            *(float4*)(pv + 8) = (float4){__uint_as_float(vp1.x << 16), __uint_as_float(vp1.x & 0xffff0000u),
                                          __uint_as_float(vp1.y << 16), __uint_as_float(vp1.y & 0xffff0000u)};
            *(float4*)(pv + 12)= (float4){__uint_as_float(vp1.z << 16), __uint_as_float(vp1.z & 0xffff0000u),
                                          __uint_as_float(vp1.w << 16), __uint_as_float(vp1.w & 0xffff0000u)};
        }
        __syncthreads();
#pragma unroll 8
        for (int s = 0; s < 64; ++s) {
            const float kd = sK[s][d];
            zacc += kd;                              // committed only by mg==0
            const f32x4* vr = (const f32x4*)(&sV[s][m0]);
            acc[0] += kd * vr[0];
            acc[1] += kd * vr[1];
            acc[2] += kd * vr[2];
            acc[3] += kd * vr[3];
        }
    }
    float* kvp = kvz + ((size_t)bh * 64 + d) * 64 + m0;
#pragma unroll
    for (int c = 0; c < 4; ++c)
#pragma unroll
        for (int j = 0; j < 4; ++j)
            atomicAdd(kvp + c * 4 + j, acc[c][j]);
    if (mg == 0) atomicAdd(kvz + KV_ELEMS + bh * 64 + d, zacc);
}

// ---------------- attention: y = (Q @ kv) / (Q . z + eps), per (b,h) ------------
__global__ __launch_bounds__(256, 4)
void attn_kernel(const uint16_t* __restrict__ Qb, const float* __restrict__ kvz,
                 uint16_t* __restrict__ Yb)
{
    __shared__ uint4 smem4[1152];             // 10 KB frag + 8 KB epilogue scratch
    uint16_t* sB = (uint16_t*)smem4;          // 5120 entries
    uint16_t* sEp = (uint16_t*)(smem4 + 640); // 4 x 1024 entries
    const int bh = blockIdx.y;
    const int b = bh >> 3, h = bh & 7;
    const float* kv = kvz + (size_t)bh * (DHEAD * DHEAD);
    const float* z  = kvz + KV_ELEMS + (size_t)bh * DHEAD;
    const int tid = threadIdx.x;
    for (int e = tid; e < 80 * 64; e += 256) {
        const int n = e >> 6, d = e & 63;
        float val = (n < 64) ? kv[d * 64 + n] : ((n == 64) ? z[d] : 0.f);
        const int dst = ((((n >> 4) * 2 + (d >> 5)) * 4 + ((d >> 3) & 3)) * 16 + (n & 15)) * 8 + (d & 7);
        sB[dst] = f2bf(val);
    }
    __syncthreads();
    const int lane = tid & 63, w = tid >> 6, quad = lane >> 4, l15 = lane & 15;
    f32x4 acc[2][5];
#pragma unroll
    for (int mi = 0; mi < 2; ++mi)
#pragma unroll
        for (int ni = 0; ni < 5; ++ni) acc[mi][ni] = (f32x4){0.f, 0.f, 0.f, 0.f};
    const int row0 = blockIdx.x * 128 + w * 32;
#pragma unroll
    for (int kk = 0; kk < 2; ++kk) {
        bf16x8 afr[2];
#pragma unroll
        for (int mi = 0; mi < 2; ++mi) {
            const size_t ga = (size_t)(b * S_LEN + row0 + mi * 16 + l15) * DMODEL
                              + h * DHEAD + kk * 32 + quad * 8;
            afr[mi] = *(const bf16x8*)(Qb + ga);
        }
#pragma unroll
        for (int ni = 0; ni < 5; ++ni) {
            bf16x8 bfr = *(const bf16x8*)(sB + ((ni * 2 + kk) * 64 + lane) * 8);
            acc[0][ni] = __builtin_amdgcn_mfma_f32_16x16x32_bf16(afr[0], bfr, acc[0][ni], 0, 0, 0);
            acc[1][ni] = __builtin_amdgcn_mfma_f32_16x16x32_bf16(afr[1], bfr, acc[1][ni], 0, 0, 0);
        }
    }
    uint16_t* t = sEp + w * 1024;             // 2 KB per-wave scratch (no barrier needed)
#pragma unroll
    for (int mi = 0; mi < 2; ++mi) {
        float rden[4];
#pragma unroll
        for (int r = 0; r < 4; ++r) {
            const float den = __shfl(acc[mi][4][r], lane & 48, 64);  // col 64 = l15==0
            rden[r] = 1.0f / (den + 1e-6f);
        }
#pragma unroll
        for (int ni = 0; ni < 4; ++ni)
#pragma unroll
            for (int r = 0; r < 4; ++r)
                t[(quad * 4 + r) * 64 + ni * 16 + l15] = f2bf(acc[mi][ni][r] * rden[r]);
#pragma unroll
        for (int c = 0; c < 2; ++c) {
            const int idx = c * 64 + lane;
            const int row = idx >> 3, colc = (idx & 7) * 8;
            uint4 vv = *(const uint4*)(t + row * 64 + colc);
            *(uint4*)(Yb + (size_t)(b * S_LEN + row0 + mi * 16 + row) * 512
                        + h * DHEAD + colc) = vv;
        }
    }
}

extern "C" void kernel_launch(void* const* d_in, const int* in_sizes, int n_in,
                              void* d_out, int out_size, void* d_ws, size_t ws_size,
                              hipStream_t stream)
{
    const float* q  = (const float*)d_in[0];
    const float* k  = (const float*)d_in[1];
    const float* v  = (const float*)d_in[2];
    const float* Wq = (const float*)d_in[3];
    const float* bq = (const float*)d_in[4];
    const float* Wk = (const float*)d_in[5];
    const float* bk = (const float*)d_in[6];
    const float* Wv = (const float*)d_in[7];
    const float* bv = (const float*)d_in[8];
    const float* Wo = (const float*)d_in[9];
    const float* bo = (const float*)d_in[10];

    uint16_t* Qb = (uint16_t*)d_ws;          // bf16 [32768][512]
    uint16_t* Kb = Qb + OUT0_ELEMS;
    uint16_t* Vb = Kb + OUT0_ELEMS;
    uint16_t* Wb = Vb + OUT0_ELEMS;          // 4 x [512][512] bf16
    uint16_t* Yb = Kb;                       // K dead after kv_kernel -> reuse

    float* out0 = (float*)d_out;
    float* kvz  = out0 + OUT0_ELEMS;         // kv (131072) then z (2048)

    hipMemsetAsync(kvz, 0, (KV_ELEMS + Z_ELEMS) * sizeof(float), stream);
    wconv_kernel<<<dim3(256, 4), 256, 0, stream>>>(Wq, Wk, Wv, Wo, Wb);
    gemm_kernel<true, true,  false><<<dim3(4, 256), 256, 0, stream>>>(q, Wb,              bq, Qb);
    gemm_kernel<true, true,  false><<<dim3(4, 256), 256, 0, stream>>>(k, Wb + 262144,     bk, Kb);
    gemm_kernel<true, false, false><<<dim3(4, 256), 256, 0, stream>>>(v, Wb + 2 * 262144, bv, Vb);
    kv_kernel<<<dim3(32, 16), 256, 0, stream>>>(Kb, Vb, kvz);
    attn_kernel<<<dim3(64, 32), 256, 0, stream>>>(Qb, kvz, Yb);
    gemm_kernel<false, false, true><<<dim3(4, 256), 256, 0, stream>>>(Yb, Wb + 3 * 262144, bo, out0);
}

// Round 3
// 431.660 us; speedup vs baseline: 3.0423x; 1.3580x over previous
//
#include <hip/hip_runtime.h>
#include <hip/hip_bf16.h>
#include <stdint.h>

typedef __bf16 bf16x8 __attribute__((ext_vector_type(8)));
typedef float f32x4 __attribute__((ext_vector_type(4)));

#define S_LEN 8192
#define BATCH 4
#define DMODEL 512
#define NHEAD 8
#define DHEAD 64
#define MROWS (BATCH * S_LEN)              // 32768
#define OUT0_ELEMS (MROWS * DMODEL)        // 16777216
#define KV_ELEMS (BATCH * NHEAD * DHEAD * DHEAD)  // 131072
#define Z_ELEMS (BATCH * NHEAD * DHEAD)    // 2048

__device__ __forceinline__ uint16_t f2bf(float f) {
    uint32_t u = __float_as_uint(f);
    u = (u + 0x7fffu + ((u >> 16) & 1u)) >> 16;   // RNE
    return (uint16_t)u;
}
__device__ __forceinline__ uint32_t pack2(float a, float b) {
    union { __hip_bfloat162 h; uint32_t u; } cv;
    cv.h = __float22bfloat162_rn(make_float2(a, b));
    return cv.u;
}
__device__ __forceinline__ void gload_lds16(const void* g, void* l) {
    __builtin_amdgcn_global_load_lds(
        (const __attribute__((address_space(1))) void*)g,
        (__attribute__((address_space(3))) void*)l, 16, 0, 0);
}

// ---------------- weights fp32 -> bf16 (all four at once) ----------------
__global__ void wconv_kernel(const float* __restrict__ w0, const float* __restrict__ w1,
                             const float* __restrict__ w2, const float* __restrict__ w3,
                             uint16_t* __restrict__ dst) {
    const float* src = (blockIdx.y == 0) ? w0 : (blockIdx.y == 1) ? w1
                       : (blockIdx.y == 2) ? w2 : w3;
    uint16_t* d = dst + (size_t)blockIdx.y * (DMODEL * DMODEL);
    int i = (blockIdx.x * 256 + threadIdx.x) * 4;
    float4 v = *(const float4*)(src + i);
    uint2 o;
    o.x = pack2(v.x, v.y);
    o.y = pack2(v.z, v.w);
    *(uint2*)(d + i) = o;
}

// ---------------- GEMM: C[m][n] = act(sum_k A[m][k]*W[n][k] + bias[n]) ----------
// 128x128 tile, BK=32, 4 waves each 64x64 (4x4 of 16x16x32 MFMA), packed-fragment LDS.
// OUT_TRANS: write C^T as [b][col][s] bf16 (for KT/VT feeding the kv MFMA GEMM).
template<bool A_F32, bool ELU1, bool OUT_F32, bool OUT_TRANS>
__global__ __launch_bounds__(256, 3)
void gemm_kernel(const void* __restrict__ Ap, const uint16_t* __restrict__ Wb,
                 const float* __restrict__ bias, void* __restrict__ Cp)
{
    __shared__ uint4 smem4[1280];            // 20 KB (k-loop: sA 8K + sB 8K; epilogue scratch)
    uint16_t* sA = (uint16_t*)smem4;
    uint16_t* sB = (uint16_t*)(smem4 + 512);
    const int tid = threadIdx.x;
    const int lane = tid & 63, w = tid >> 6;
    const int quad = lane >> 4, l15 = lane & 15;
    const int m_blk = blockIdx.y * 128, n_blk = blockIdx.x * 128;

    f32x4 acc[4][4];
#pragma unroll
    for (int mi = 0; mi < 4; ++mi)
#pragma unroll
        for (int ni = 0; ni < 4; ++ni) acc[mi][ni] = (f32x4){0.f, 0.f, 0.f, 0.f};

    const int ar = tid >> 1;      // A fp32 staging: row 0..127
    const int ah = tid & 1;       // k-half (16 cols)
    const int g0 = w * 2;         // this wave's two LDS staging groups

    for (int kk = 0; kk < 16; ++kk) {
        const int k0 = kk * 32;
        uint4 p0, p1;
        if (A_F32) {
            const float* arow = (const float*)Ap + (size_t)(m_blk + ar) * 512 + k0 + ah * 16;
            float4 a0 = *(const float4*)(arow);
            float4 a1 = *(const float4*)(arow + 4);
            float4 a2 = *(const float4*)(arow + 8);
            float4 a3 = *(const float4*)(arow + 12);
            p0 = make_uint4(pack2(a0.x, a0.y), pack2(a0.z, a0.w),
                            pack2(a1.x, a1.y), pack2(a1.z, a1.w));
            p1 = make_uint4(pack2(a2.x, a2.y), pack2(a2.z, a2.w),
                            pack2(a3.x, a3.y), pack2(a3.z, a3.w));
        }
        __syncthreads();   // previous iteration's fragment reads complete
        gload_lds16(Wb + (size_t)(n_blk + g0 * 16 + l15) * 512 + k0 + quad * 8,
                    sB + g0 * 512);
        gload_lds16(Wb + (size_t)(n_blk + (g0 + 1) * 16 + l15) * 512 + k0 + quad * 8,
                    sB + (g0 + 1) * 512);
        if (A_F32) {
            uint16_t* base = sA + (((ar >> 4) * 4 + ah * 2) * 16 + (ar & 15)) * 8;
            *(uint4*)base = p0;
            *(uint4*)(base + 128) = p1;
        } else {
            const uint16_t* Ab = (const uint16_t*)Ap;
            gload_lds16(Ab + (size_t)(m_blk + g0 * 16 + l15) * 512 + k0 + quad * 8,
                        sA + g0 * 512);
            gload_lds16(Ab + (size_t)(m_blk + (g0 + 1) * 16 + l15) * 512 + k0 + quad * 8,
                        sA + (g0 + 1) * 512);
        }
        __syncthreads();
        bf16x8 afr[4], bfr[4];
#pragma unroll
        for (int mi = 0; mi < 4; ++mi)
            afr[mi] = *(const bf16x8*)(sA + (((w & 1) * 4 + mi) * 64 + lane) * 8);
#pragma unroll
        for (int ni = 0; ni < 4; ++ni)
            bfr[ni] = *(const bf16x8*)(sB + (((w >> 1) * 4 + ni) * 64 + lane) * 8);
#pragma unroll
        for (int mi = 0; mi < 4; ++mi)
#pragma unroll
            for (int ni = 0; ni < 4; ++ni)
                acc[mi][ni] = __builtin_amdgcn_mfma_f32_16x16x32_bf16(
                    afr[mi], bfr[ni], acc[mi][ni], 0, 0, 0);
    }
    __syncthreads();       // k-loop LDS dead; reuse as epilogue scratch

    const int mw = (w & 1) * 64, nw = (w >> 1) * 64;
    float bias4[4];
#pragma unroll
    for (int ni = 0; ni < 4; ++ni) bias4[ni] = bias[n_blk + nw + ni * 16 + l15];

    if (OUT_TRANS) {
        // per-wave scratch: 64 cols x 32 rows, stride 40 (bank spread, 16B-aligned)
        uint16_t* t = (uint16_t*)smem4 + w * 2560;
        uint16_t* C = (uint16_t*)Cp;
        const int bb = m_blk >> 13;
        const int s_base = (m_blk & 8191) + mw;
#pragma unroll
        for (int p = 0; p < 2; ++p) {
#pragma unroll
            for (int mi2 = 0; mi2 < 2; ++mi2) {
                const int mi = p * 2 + mi2;
#pragma unroll
                for (int ni = 0; ni < 4; ++ni)
#pragma unroll
                    for (int r = 0; r < 4; ++r) {
                        float val = acc[mi][ni][r] + bias4[ni];
                        if (ELU1) val = (val > 0.f) ? (val + 1.f) : __expf(val);
                        t[(ni * 16 + l15) * 40 + mi2 * 16 + quad * 4 + r] = f2bf(val);
                    }
            }
#pragma unroll
            for (int it = 0; it < 4; ++it) {
                const int idx = it * 64 + lane;
                const int col = idx >> 2, sg = idx & 3;
                uint4 vv = *(const uint4*)(t + col * 40 + sg * 8);
                *(uint4*)(C + ((size_t)(bb * 512) + n_blk + nw + col) * 8192
                            + s_base + p * 32 + sg * 8) = vv;
            }
        }
    } else if (OUT_F32) {
        float* t = (float*)(smem4 + w * 256);
        float* C = (float*)Cp;
#pragma unroll
        for (int mi = 0; mi < 4; ++mi) {
#pragma unroll
            for (int ni = 0; ni < 4; ++ni)
#pragma unroll
                for (int r = 0; r < 4; ++r) {
                    float val = acc[mi][ni][r] + bias4[ni];
                    if (ELU1) val = (val > 0.f) ? (val + 1.f) : __expf(val);
                    t[(quad * 4 + r) * 64 + ni * 16 + l15] = val;
                }
#pragma unroll
            for (int c = 0; c < 4; ++c) {
                const int idx = c * 64 + lane;
                const int row = idx >> 4, colc = (idx & 15) * 4;
                float4 vv = *(const float4*)(t + row * 64 + colc);
                *(float4*)(C + (size_t)(m_blk + mw + mi * 16 + row) * 512
                             + n_blk + nw + colc) = vv;
            }
        }
    } else {
        uint16_t* t = (uint16_t*)(smem4 + w * 128);
        uint16_t* C = (uint16_t*)Cp;
#pragma unroll
        for (int mi = 0; mi < 4; ++mi) {
#pragma unroll
            for (int ni = 0; ni < 4; ++ni)
#pragma unroll
                for (int r = 0; r < 4; ++r) {
                    float val = acc[mi][ni][r] + bias4[ni];
                    if (ELU1) val = (val > 0.f) ? (val + 1.f) : __expf(val);
                    t[(quad * 4 + r) * 64 + ni * 16 + l15] = f2bf(val);
                }
#pragma unroll
            for (int c = 0; c < 2; ++c) {
                const int idx = c * 64 + lane;
                const int row = idx >> 3, colc = (idx & 7) * 8;
                uint4 vv = *(const uint4*)(t + row * 64 + colc);
                *(uint4*)(C + (size_t)(m_blk + mw + mi * 16 + row) * 512
                            + n_blk + nw + colc) = vv;
            }
        }
    }
}

// ---------------- kv state via MFMA: kv[d][m] = sum_s KT[d][s]*VT[m][s] ---------
// Per (b,h): 64x64x8192 GEMM, 16 s-splits of 512, BK=64. z[d]=sum_s KT[d][s] folded
// in as MFMA against a constant all-ones B fragment. fp32 atomicAdd commit.
__global__ __launch_bounds__(256)
void kv_kernel(const uint16_t* __restrict__ KT, const uint16_t* __restrict__ VT,
               float* __restrict__ kvz)
{
    __shared__ uint16_t sA[4096];   // [g(4)][kk(2)][lane(64)][8]
    __shared__ uint16_t sB[4096];
    const int tid = threadIdx.x;
    const int lane = tid & 63, w = tid >> 6;
    const int quad = lane >> 4, l15 = lane & 15;
    const int bh = blockIdx.y, b = bh >> 3, h = bh & 7;
    const int dh2 = w & 1, mh2 = w >> 1;
    const int S0 = blockIdx.x * 512;

    const uint16_t* Arow = KT + ((size_t)(b * 512 + h * 64 + w * 16 + l15)) * 8192 + S0;
    const uint16_t* Brow = VT + ((size_t)(b * 512 + h * 64 + w * 16 + l15)) * 8192 + S0;

    f32x4 acc[2][2], accz[2];
#pragma unroll
    for (int mi = 0; mi < 2; ++mi) {
        accz[mi] = (f32x4){0.f, 0.f, 0.f, 0.f};
#pragma unroll
        for (int ni = 0; ni < 2; ++ni) acc[mi][ni] = (f32x4){0.f, 0.f, 0.f, 0.f};
    }
    bf16x8 ones;
#pragma unroll
    for (int j = 0; j < 8; ++j) ones[j] = (__bf16)1.0f;

    for (int it = 0; it < 8; ++it) {
        const int soff = it * 64;
        __syncthreads();
#pragma unroll
        for (int c = 0; c < 2; ++c) {
            gload_lds16(Arow + soff + (quad + 4 * c) * 8, sA + (w * 2 + c) * 512);
            gload_lds16(Brow + soff + (quad + 4 * c) * 8, sB + (w * 2 + c) * 512);
        }
        __syncthreads();
#pragma unroll
        for (int kk = 0; kk < 2; ++kk) {
            bf16x8 afr[2], bfr[2];
#pragma unroll
            for (int mi = 0; mi < 2; ++mi)
                afr[mi] = *(const bf16x8*)(sA + (((dh2 * 2 + mi) * 2 + kk) * 64 + lane) * 8);
#pragma unroll
            for (int ni = 0; ni < 2; ++ni)
                bfr[ni] = *(const bf16x8*)(sB + (((mh2 * 2 + ni) * 2 + kk) * 64 + lane) * 8);
#pragma unroll
            for (int mi = 0; mi < 2; ++mi)
#pragma unroll
                for (int ni = 0; ni < 2; ++ni)
                    acc[mi][ni] = __builtin_amdgcn_mfma_f32_16x16x32_bf16(
                        afr[mi], bfr[ni], acc[mi][ni], 0, 0, 0);
            if (mh2 == 0) {
#pragma unroll
                for (int mi = 0; mi < 2; ++mi)
                    accz[mi] = __builtin_amdgcn_mfma_f32_16x16x32_bf16(
                        afr[mi], ones, accz[mi], 0, 0, 0);
            }
        }
    }
    float* kvp = kvz + (size_t)bh * 4096;
#pragma unroll
    for (int mi = 0; mi < 2; ++mi)
#pragma unroll
        for (int ni = 0; ni < 2; ++ni)
#pragma unroll
            for (int r = 0; r < 4; ++r)
                atomicAdd(kvp + (dh2 * 32 + mi * 16 + quad * 4 + r) * 64
                              + mh2 * 32 + ni * 16 + l15, acc[mi][ni][r]);
    if (mh2 == 0 && l15 == 0) {
#pragma unroll
        for (int mi = 0; mi < 2; ++mi)
#pragma unroll
            for (int r = 0; r < 4; ++r)
                atomicAdd(kvz + KV_ELEMS + bh * 64 + dh2 * 32 + mi * 16 + quad * 4 + r,
                          accz[mi][r]);
    }
}

// ---------------- kv finalize: fp32 kv+z -> bf16 fragment-layout KVf ------------
// KVf[bh] flat order: [ng(5)][kk(2)][quad(4)][l15(16)][j(8)], n=ng*16+l15,
// d=kk*32+quad*8+j; n==64 -> z column, n>64 -> 0 pad.
__global__ void kvf_kernel(const float* __restrict__ kvz, uint16_t* __restrict__ KVf) {
    const int bh = blockIdx.x;
    const int tid = threadIdx.x;
    for (int e = tid; e < 5120; e += 256) {
        const int j = e & 7, c = e >> 3;
        const int l15c = c & 15, quadc = (c >> 4) & 3, kkc = (c >> 6) & 1, ng = c >> 7;
        const int n = ng * 16 + l15c;
        const int d = kkc * 32 + quadc * 8 + j;
        float val = (n < 64) ? kvz[(size_t)bh * 4096 + d * 64 + n]
                  : ((n == 64) ? kvz[KV_ELEMS + bh * 64 + d] : 0.f);
        KVf[(size_t)bh * 5120 + e] = f2bf(val);
    }
}

// ---------------- attention: y = (Q @ kv) / (Q . z + eps), per (b,h) ------------
__global__ __launch_bounds__(256, 4)
void attn_kernel(const uint16_t* __restrict__ Qb, const uint16_t* __restrict__ KVf,
                 uint16_t* __restrict__ Yb)
{
    __shared__ uint4 smem4[1152];             // 10 KB frag + 8 KB epilogue scratch
    uint16_t* sB = (uint16_t*)smem4;          // 5120 entries
    uint16_t* sEp = (uint16_t*)(smem4 + 640);
    const int bh = blockIdx.y;
    const int b = bh >> 3, h = bh & 7;
    const int tid = threadIdx.x;
    const int lane = tid & 63, w = tid >> 6, quad = lane >> 4, l15 = lane & 15;

    const uint16_t* src = KVf + (size_t)bh * 5120;
    gload_lds16(src + (size_t)tid * 8,         sB + (w * 64) * 8);
    gload_lds16(src + (size_t)(256 + tid) * 8, sB + ((256 + w * 64)) * 8);
    if (tid < 128)
        gload_lds16(src + (size_t)(512 + tid) * 8, sB + ((512 + w * 64)) * 8);
    __syncthreads();

    f32x4 acc[2][5];
#pragma unroll
    for (int mi = 0; mi < 2; ++mi)
#pragma unroll
        for (int ni = 0; ni < 5; ++ni) acc[mi][ni] = (f32x4){0.f, 0.f, 0.f, 0.f};
    const int row0 = blockIdx.x * 128 + w * 32;
#pragma unroll
    for (int kk = 0; kk < 2; ++kk) {
        bf16x8 afr[2];
#pragma unroll
        for (int mi = 0; mi < 2; ++mi) {
            const size_t ga = (size_t)(b * S_LEN + row0 + mi * 16 + l15) * DMODEL
                              + h * DHEAD + kk * 32 + quad * 8;
            afr[mi] = *(const bf16x8*)(Qb + ga);
        }
#pragma unroll
        for (int ni = 0; ni < 5; ++ni) {
            bf16x8 bfr = *(const bf16x8*)(sB + ((ni * 2 + kk) * 64 + lane) * 8);
            acc[0][ni] = __builtin_amdgcn_mfma_f32_16x16x32_bf16(afr[0], bfr, acc[0][ni], 0, 0, 0);
            acc[1][ni] = __builtin_amdgcn_mfma_f32_16x16x32_bf16(afr[1], bfr, acc[1][ni], 0, 0, 0);
        }
    }
    uint16_t* t = sEp + w * 1024;
#pragma unroll
    for (int mi = 0; mi < 2; ++mi) {
        float rden[4];
#pragma unroll
        for (int r = 0; r < 4; ++r) {
            const float den = __shfl(acc[mi][4][r], lane & 48, 64);  // col 64 = l15==0
            rden[r] = 1.0f / (den + 1e-6f);
        }
#pragma unroll
        for (int ni = 0; ni < 4; ++ni)
#pragma unroll
            for (int r = 0; r < 4; ++r)
                t[(quad * 4 + r) * 64 + ni * 16 + l15] = f2bf(acc[mi][ni][r] * rden[r]);
#pragma unroll
        for (int c = 0; c < 2; ++c) {
            const int idx = c * 64 + lane;
            const int row = idx >> 3, colc = (idx & 7) * 8;
            uint4 vv = *(const uint4*)(t + row * 64 + colc);
            *(uint4*)(Yb + (size_t)(b * S_LEN + row0 + mi * 16 + row) * 512
                        + h * DHEAD + colc) = vv;
        }
    }
}

extern "C" void kernel_launch(void* const* d_in, const int* in_sizes, int n_in,
                              void* d_out, int out_size, void* d_ws, size_t ws_size,
                              hipStream_t stream)
{
    const float* q  = (const float*)d_in[0];
    const float* k  = (const float*)d_in[1];
    const float* v  = (const float*)d_in[2];
    const float* Wq = (const float*)d_in[3];
    const float* bq = (const float*)d_in[4];
    const float* Wk = (const float*)d_in[5];
    const float* bk = (const float*)d_in[6];
    const float* Wv = (const float*)d_in[7];
    const float* bv = (const float*)d_in[8];
    const float* Wo = (const float*)d_in[9];
    const float* bo = (const float*)d_in[10];

    uint16_t* Qb = (uint16_t*)d_ws;          // bf16 [32768][512]
    uint16_t* KT = Qb + OUT0_ELEMS;          // bf16 [4][512][8192] keys^T
    uint16_t* VT = KT + OUT0_ELEMS;          // bf16 [4][512][8192] values^T
    uint16_t* Wb = VT + OUT0_ELEMS;          // 4 x [512][512] bf16
    uint16_t* KVf = VT;                      // VT dead after kv_kernel -> reuse
    uint16_t* Yb = KT;                       // KT dead after kv_kernel -> reuse

    float* out0 = (float*)d_out;
    float* kvz  = out0 + OUT0_ELEMS;         // kv (131072) then z (2048)

    hipMemsetAsync(kvz, 0, (KV_ELEMS + Z_ELEMS) * sizeof(float), stream);
    wconv_kernel<<<dim3(256, 4), 256, 0, stream>>>(Wq, Wk, Wv, Wo, Wb);
    gemm_kernel<true, true,  false, false><<<dim3(4, 256), 256, 0, stream>>>(q, Wb,              bq, Qb);
    gemm_kernel<true, true,  false, true ><<<dim3(4, 256), 256, 0, stream>>>(k, Wb + 262144,     bk, KT);
    gemm_kernel<true, false, false, true ><<<dim3(4, 256), 256, 0, stream>>>(v, Wb + 2 * 262144, bv, VT);
    kv_kernel<<<dim3(16, 32), 256, 0, stream>>>(KT, VT, kvz);
    kvf_kernel<<<dim3(32), 256, 0, stream>>>(kvz, KVf);
    attn_kernel<<<dim3(64, 32), 256, 0, stream>>>(Qb, KVf, Yb);
    gemm_kernel<false, false, true, false><<<dim3(4, 256), 256, 0, stream>>>(Yb, Wb + 3 * 262144, bo, out0);
}

// Round 4
// 414.761 us; speedup vs baseline: 3.1662x; 1.0407x over previous
//
#include <hip/hip_runtime.h>
#include <hip/hip_bf16.h>
#include <stdint.h>

typedef __bf16 bf16x8 __attribute__((ext_vector_type(8)));
typedef float f32x4 __attribute__((ext_vector_type(4)));

#define S_LEN 8192
#define BATCH 4
#define DMODEL 512
#define NHEAD 8
#define DHEAD 64
#define MROWS (BATCH * S_LEN)              // 32768
#define OUT0_ELEMS (MROWS * DMODEL)        // 16777216
#define KV_ELEMS (BATCH * NHEAD * DHEAD * DHEAD)  // 131072
#define Z_ELEMS (BATCH * NHEAD * DHEAD)    // 2048

__device__ __forceinline__ uint16_t f2bf(float f) {
    uint32_t u = __float_as_uint(f);
    u = (u + 0x7fffu + ((u >> 16) & 1u)) >> 16;   // RNE
    return (uint16_t)u;
}
__device__ __forceinline__ uint32_t pack2(float a, float b) {
    union { __hip_bfloat162 h; uint32_t u; } cv;
    cv.h = __float22bfloat162_rn(make_float2(a, b));
    return cv.u;
}
__device__ __forceinline__ void gload_lds16(const void* g, void* l) {
    __builtin_amdgcn_global_load_lds(
        (const __attribute__((address_space(1))) void*)g,
        (__attribute__((address_space(3))) void*)l, 16, 0, 0);
}

// ---------------- weights fp32 -> bf16 (all four at once) ----------------
__global__ void wconv_kernel(const float* __restrict__ w0, const float* __restrict__ w1,
                             const float* __restrict__ w2, const float* __restrict__ w3,
                             uint16_t* __restrict__ dst) {
    const float* src = (blockIdx.y == 0) ? w0 : (blockIdx.y == 1) ? w1
                       : (blockIdx.y == 2) ? w2 : w3;
    uint16_t* d = dst + (size_t)blockIdx.y * (DMODEL * DMODEL);
    int i = (blockIdx.x * 256 + threadIdx.x) * 4;
    float4 v = *(const float4*)(src + i);
    uint2 o;
    o.x = pack2(v.x, v.y);
    o.y = pack2(v.z, v.w);
    *(uint2*)(d + i) = o;
}

// ---------------- GEMM: C[m][n] = act(sum_k A[m][k]*W[n][k] + bias[n]) ----------
// 128x128 tile, BK=32, 4 waves each 64x64 (4x4 of 16x16x32 MFMA), packed-fragment LDS.
// Grid (m=256, n=4): linear id = n*256+m, 256%8==0 -> the 4 n-blocks sharing an
// A m-tile land on the SAME XCD (round-robin id%8) and are co-resident -> A rereads
// hit that XCD's L2 instead of re-crossing to LLC/HBM.
// A fp32 loads are register-prefetched one K-iter ahead so pack2 never stalls on HBM.
template<bool A_F32, bool ELU1, bool OUT_F32, bool OUT_TRANS>
__global__ __launch_bounds__(256, 3)
void gemm_kernel(const void* __restrict__ Ap, const uint16_t* __restrict__ Wb,
                 const float* __restrict__ bias, void* __restrict__ Cp)
{
    __shared__ uint4 smem4[1280];            // 20 KB (k-loop: sA 8K + sB 8K; epilogue scratch)
    uint16_t* sA = (uint16_t*)smem4;
    uint16_t* sB = (uint16_t*)(smem4 + 512);
    const int tid = threadIdx.x;
    const int lane = tid & 63, w = tid >> 6;
    const int quad = lane >> 4, l15 = lane & 15;
    const int m_blk = blockIdx.x * 128, n_blk = blockIdx.y * 128;

    f32x4 acc[4][4];
#pragma unroll
    for (int mi = 0; mi < 4; ++mi)
#pragma unroll
        for (int ni = 0; ni < 4; ++ni) acc[mi][ni] = (f32x4){0.f, 0.f, 0.f, 0.f};

    const int ar = tid >> 1;      // A fp32 staging: row 0..127
    const int ah = tid & 1;       // k-half (16 cols)
    const int g0 = w * 2;         // this wave's two LDS staging groups

    const float* arow_base = A_F32 ? ((const float*)Ap + (size_t)(m_blk + ar) * 512 + ah * 16)
                                   : nullptr;
    float4 a0, a1, a2, a3;
    if (A_F32) {
        a0 = *(const float4*)(arow_base);
        a1 = *(const float4*)(arow_base + 4);
        a2 = *(const float4*)(arow_base + 8);
        a3 = *(const float4*)(arow_base + 12);
    }

    for (int kk = 0; kk < 16; ++kk) {
        const int k0 = kk * 32;
        uint4 p0, p1;
        float4 b0, b1, b2, b3;
        if (A_F32) {
            if (kk < 15) {   // issue next iter's loads BEFORE consuming current regs
                const float* arow = arow_base + (kk + 1) * 32;
                b0 = *(const float4*)(arow);
                b1 = *(const float4*)(arow + 4);
                b2 = *(const float4*)(arow + 8);
                b3 = *(const float4*)(arow + 12);
            }
            p0 = make_uint4(pack2(a0.x, a0.y), pack2(a0.z, a0.w),
                            pack2(a1.x, a1.y), pack2(a1.z, a1.w));
            p1 = make_uint4(pack2(a2.x, a2.y), pack2(a2.z, a2.w),
                            pack2(a3.x, a3.y), pack2(a3.z, a3.w));
        }
        __syncthreads();   // previous iteration's fragment reads complete
        gload_lds16(Wb + (size_t)(n_blk + g0 * 16 + l15) * 512 + k0 + quad * 8,
                    sB + g0 * 512);
        gload_lds16(Wb + (size_t)(n_blk + (g0 + 1) * 16 + l15) * 512 + k0 + quad * 8,
                    sB + (g0 + 1) * 512);
        if (A_F32) {
            uint16_t* base = sA + (((ar >> 4) * 4 + ah * 2) * 16 + (ar & 15)) * 8;
            *(uint4*)base = p0;
            *(uint4*)(base + 128) = p1;
            if (kk < 15) { a0 = b0; a1 = b1; a2 = b2; a3 = b3; }
        } else {
            const uint16_t* Ab = (const uint16_t*)Ap;
            gload_lds16(Ab + (size_t)(m_blk + g0 * 16 + l15) * 512 + k0 + quad * 8,
                        sA + g0 * 512);
            gload_lds16(Ab + (size_t)(m_blk + (g0 + 1) * 16 + l15) * 512 + k0 + quad * 8,
                        sA + (g0 + 1) * 512);
        }
        __syncthreads();
        bf16x8 afr[4], bfr[4];
#pragma unroll
        for (int mi = 0; mi < 4; ++mi)
            afr[mi] = *(const bf16x8*)(sA + (((w & 1) * 4 + mi) * 64 + lane) * 8);
#pragma unroll
        for (int ni = 0; ni < 4; ++ni)
            bfr[ni] = *(const bf16x8*)(sB + (((w >> 1) * 4 + ni) * 64 + lane) * 8);
#pragma unroll
        for (int mi = 0; mi < 4; ++mi)
#pragma unroll
            for (int ni = 0; ni < 4; ++ni)
                acc[mi][ni] = __builtin_amdgcn_mfma_f32_16x16x32_bf16(
                    afr[mi], bfr[ni], acc[mi][ni], 0, 0, 0);
    }
    __syncthreads();       // k-loop LDS dead; reuse as epilogue scratch

    const int mw = (w & 1) * 64, nw = (w >> 1) * 64;
    float bias4[4];
#pragma unroll
    for (int ni = 0; ni < 4; ++ni) bias4[ni] = bias[n_blk + nw + ni * 16 + l15];

    if (OUT_TRANS) {
        // per-wave scratch: 64 cols x 32 rows, stride 40 (bank spread, 16B-aligned)
        uint16_t* t = (uint16_t*)smem4 + w * 2560;
        uint16_t* C = (uint16_t*)Cp;
        const int bb = m_blk >> 13;
        const int s_base = (m_blk & 8191) + mw;
#pragma unroll
        for (int p = 0; p < 2; ++p) {
#pragma unroll
            for (int mi2 = 0; mi2 < 2; ++mi2) {
                const int mi = p * 2 + mi2;
#pragma unroll
                for (int ni = 0; ni < 4; ++ni)
#pragma unroll
                    for (int r = 0; r < 4; ++r) {
                        float val = acc[mi][ni][r] + bias4[ni];
                        if (ELU1) val = (val > 0.f) ? (val + 1.f) : __expf(val);
                        t[(ni * 16 + l15) * 40 + mi2 * 16 + quad * 4 + r] = f2bf(val);
                    }
            }
#pragma unroll
            for (int it = 0; it < 4; ++it) {
                const int idx = it * 64 + lane;
                const int col = idx >> 2, sg = idx & 3;
                uint4 vv = *(const uint4*)(t + col * 40 + sg * 8);
                *(uint4*)(C + ((size_t)(bb * 512) + n_blk + nw + col) * 8192
                            + s_base + p * 32 + sg * 8) = vv;
            }
        }
    } else if (OUT_F32) {
        float* t = (float*)(smem4 + w * 256);
        float* C = (float*)Cp;
#pragma unroll
        for (int mi = 0; mi < 4; ++mi) {
#pragma unroll
            for (int ni = 0; ni < 4; ++ni)
#pragma unroll
                for (int r = 0; r < 4; ++r) {
                    float val = acc[mi][ni][r] + bias4[ni];
                    if (ELU1) val = (val > 0.f) ? (val + 1.f) : __expf(val);
                    t[(quad * 4 + r) * 64 + ni * 16 + l15] = val;
                }
#pragma unroll
            for (int c = 0; c < 4; ++c) {
                const int idx = c * 64 + lane;
                const int row = idx >> 4, colc = (idx & 15) * 4;
                float4 vv = *(const float4*)(t + row * 64 + colc);
                *(float4*)(C + (size_t)(m_blk + mw + mi * 16 + row) * 512
                             + n_blk + nw + colc) = vv;
            }
        }
    } else {
        uint16_t* t = (uint16_t*)(smem4 + w * 128);
        uint16_t* C = (uint16_t*)Cp;
#pragma unroll
        for (int mi = 0; mi < 4; ++mi) {
#pragma unroll
            for (int ni = 0; ni < 4; ++ni)
#pragma unroll
                for (int r = 0; r < 4; ++r) {
                    float val = acc[mi][ni][r] + bias4[ni];
                    if (ELU1) val = (val > 0.f) ? (val + 1.f) : __expf(val);
                    t[(quad * 4 + r) * 64 + ni * 16 + l15] = f2bf(val);
                }
#pragma unroll
            for (int c = 0; c < 2; ++c) {
                const int idx = c * 64 + lane;
                const int row = idx >> 3, colc = (idx & 7) * 8;
                uint4 vv = *(const uint4*)(t + row * 64 + colc);
                *(uint4*)(C + (size_t)(m_blk + mw + mi * 16 + row) * 512
                            + n_blk + nw + colc) = vv;
            }
        }
    }
}

// ---------------- kv state via MFMA: kv[d][m] = sum_s KT[d][s]*VT[m][s] ---------
// Per (b,h): 64x64x8192 GEMM, 16 s-splits of 512, BK=64. z[d]=sum_s KT[d][s] folded
// in as MFMA against a constant all-ones B fragment. fp32 atomicAdd commit.
__global__ __launch_bounds__(256)
void kv_kernel(const uint16_t* __restrict__ KT, const uint16_t* __restrict__ VT,
               float* __restrict__ kvz)
{
    __shared__ uint16_t sA[4096];   // [g(4)][kk(2)][lane(64)][8]
    __shared__ uint16_t sB[4096];
    const int tid = threadIdx.x;
    const int lane = tid & 63, w = tid >> 6;
    const int quad = lane >> 4, l15 = lane & 15;
    const int bh = blockIdx.y, b = bh >> 3, h = bh & 7;
    const int dh2 = w & 1, mh2 = w >> 1;
    const int S0 = blockIdx.x * 512;

    const uint16_t* Arow = KT + ((size_t)(b * 512 + h * 64 + w * 16 + l15)) * 8192 + S0;
    const uint16_t* Brow = VT + ((size_t)(b * 512 + h * 64 + w * 16 + l15)) * 8192 + S0;

    f32x4 acc[2][2], accz[2];
#pragma unroll
    for (int mi = 0; mi < 2; ++mi) {
        accz[mi] = (f32x4){0.f, 0.f, 0.f, 0.f};
#pragma unroll
        for (int ni = 0; ni < 2; ++ni) acc[mi][ni] = (f32x4){0.f, 0.f, 0.f, 0.f};
    }
    bf16x8 ones;
#pragma unroll
    for (int j = 0; j < 8; ++j) ones[j] = (__bf16)1.0f;

    for (int it = 0; it < 8; ++it) {
        const int soff = it * 64;
        __syncthreads();
#pragma unroll
        for (int c = 0; c < 2; ++c) {
            gload_lds16(Arow + soff + (quad + 4 * c) * 8, sA + (w * 2 + c) * 512);
            gload_lds16(Brow + soff + (quad + 4 * c) * 8, sB + (w * 2 + c) * 512);
        }
        __syncthreads();
#pragma unroll
        for (int kk = 0; kk < 2; ++kk) {
            bf16x8 afr[2], bfr[2];
#pragma unroll
            for (int mi = 0; mi < 2; ++mi)
                afr[mi] = *(const bf16x8*)(sA + (((dh2 * 2 + mi) * 2 + kk) * 64 + lane) * 8);
#pragma unroll
            for (int ni = 0; ni < 2; ++ni)
                bfr[ni] = *(const bf16x8*)(sB + (((mh2 * 2 + ni) * 2 + kk) * 64 + lane) * 8);
#pragma unroll
            for (int mi = 0; mi < 2; ++mi)
#pragma unroll
                for (int ni = 0; ni < 2; ++ni)
                    acc[mi][ni] = __builtin_amdgcn_mfma_f32_16x16x32_bf16(
                        afr[mi], bfr[ni], acc[mi][ni], 0, 0, 0);
            if (mh2 == 0) {
#pragma unroll
                for (int mi = 0; mi < 2; ++mi)
                    accz[mi] = __builtin_amdgcn_mfma_f32_16x16x32_bf16(
                        afr[mi], ones, accz[mi], 0, 0, 0);
            }
        }
    }
    float* kvp = kvz + (size_t)bh * 4096;
#pragma unroll
    for (int mi = 0; mi < 2; ++mi)
#pragma unroll
        for (int ni = 0; ni < 2; ++ni)
#pragma unroll
            for (int r = 0; r < 4; ++r)
                atomicAdd(kvp + (dh2 * 32 + mi * 16 + quad * 4 + r) * 64
                              + mh2 * 32 + ni * 16 + l15, acc[mi][ni][r]);
    if (mh2 == 0 && l15 == 0) {
#pragma unroll
        for (int mi = 0; mi < 2; ++mi)
#pragma unroll
            for (int r = 0; r < 4; ++r)
                atomicAdd(kvz + KV_ELEMS + bh * 64 + dh2 * 32 + mi * 16 + quad * 4 + r,
                          accz[mi][r]);
    }
}

// ---------------- kv finalize: fp32 kv+z -> bf16 fragment-layout KVf ------------
// KVf[bh] flat order: [ng(5)][kk(2)][quad(4)][l15(16)][j(8)], n=ng*16+l15,
// d=kk*32+quad*8+j; n==64 -> z column, n>64 -> 0 pad.
__global__ void kvf_kernel(const float* __restrict__ kvz, uint16_t* __restrict__ KVf) {
    const int bh = blockIdx.x;
    const int tid = threadIdx.x;
    for (int e = tid; e < 5120; e += 256) {
        const int j = e & 7, c = e >> 3;
        const int l15c = c & 15, quadc = (c >> 4) & 3, kkc = (c >> 6) & 1, ng = c >> 7;
        const int n = ng * 16 + l15c;
        const int d = kkc * 32 + quadc * 8 + j;
        float val = (n < 64) ? kvz[(size_t)bh * 4096 + d * 64 + n]
                  : ((n == 64) ? kvz[KV_ELEMS + bh * 64 + d] : 0.f);
        KVf[(size_t)bh * 5120 + e] = f2bf(val);
    }
}

// ---------------- attention: y = (Q @ kv) / (Q . z + eps), per (b,h) ------------
__global__ __launch_bounds__(256, 4)
void attn_kernel(const uint16_t* __restrict__ Qb, const uint16_t* __restrict__ KVf,
                 uint16_t* __restrict__ Yb)
{
    __shared__ uint4 smem4[1152];             // 10 KB frag + 8 KB epilogue scratch
    uint16_t* sB = (uint16_t*)smem4;          // 5120 entries
    uint16_t* sEp = (uint16_t*)(smem4 + 640);
    const int bh = blockIdx.y;
    const int b = bh >> 3, h = bh & 7;
    const int tid = threadIdx.x;
    const int lane = tid & 63, w = tid >> 6, quad = lane >> 4, l15 = lane & 15;

    const uint16_t* src = KVf + (size_t)bh * 5120;
    gload_lds16(src + (size_t)tid * 8,         sB + (w * 64) * 8);
    gload_lds16(src + (size_t)(256 + tid) * 8, sB + ((256 + w * 64)) * 8);
    if (tid < 128)
        gload_lds16(src + (size_t)(512 + tid) * 8, sB + ((512 + w * 64)) * 8);
    __syncthreads();

    f32x4 acc[2][5];
#pragma unroll
    for (int mi = 0; mi < 2; ++mi)
#pragma unroll
        for (int ni = 0; ni < 5; ++ni) acc[mi][ni] = (f32x4){0.f, 0.f, 0.f, 0.f};
    const int row0 = blockIdx.x * 128 + w * 32;
#pragma unroll
    for (int kk = 0; kk < 2; ++kk) {
        bf16x8 afr[2];
#pragma unroll
        for (int mi = 0; mi < 2; ++mi) {
            const size_t ga = (size_t)(b * S_LEN + row0 + mi * 16 + l15) * DMODEL
                              + h * DHEAD + kk * 32 + quad * 8;
            afr[mi] = *(const bf16x8*)(Qb + ga);
        }
#pragma unroll
        for (int ni = 0; ni < 5; ++ni) {
            bf16x8 bfr = *(const bf16x8*)(sB + ((ni * 2 + kk) * 64 + lane) * 8);
            acc[0][ni] = __builtin_amdgcn_mfma_f32_16x16x32_bf16(afr[0], bfr, acc[0][ni], 0, 0, 0);
            acc[1][ni] = __builtin_amdgcn_mfma_f32_16x16x32_bf16(afr[1], bfr, acc[1][ni], 0, 0, 0);
        }
    }
    uint16_t* t = sEp + w * 1024;
#pragma unroll
    for (int mi = 0; mi < 2; ++mi) {
        float rden[4];
#pragma unroll
        for (int r = 0; r < 4; ++r) {
            const float den = __shfl(acc[mi][4][r], lane & 48, 64);  // col 64 = l15==0
            rden[r] = 1.0f / (den + 1e-6f);
        }
#pragma unroll
        for (int ni = 0; ni < 4; ++ni)
#pragma unroll
            for (int r = 0; r < 4; ++r)
                t[(quad * 4 + r) * 64 + ni * 16 + l15] = f2bf(acc[mi][ni][r] * rden[r]);
#pragma unroll
        for (int c = 0; c < 2; ++c) {
            const int idx = c * 64 + lane;
            const int row = idx >> 3, colc = (idx & 7) * 8;
            uint4 vv = *(const uint4*)(t + row * 64 + colc);
            *(uint4*)(Yb + (size_t)(b * S_LEN + row0 + mi * 16 + row) * 512
                        + h * DHEAD + colc) = vv;
        }
    }
}

extern "C" void kernel_launch(void* const* d_in, const int* in_sizes, int n_in,
                              void* d_out, int out_size, void* d_ws, size_t ws_size,
                              hipStream_t stream)
{
    const float* q  = (const float*)d_in[0];
    const float* k  = (const float*)d_in[1];
    const float* v  = (const float*)d_in[2];
    const float* Wq = (const float*)d_in[3];
    const float* bq = (const float*)d_in[4];
    const float* Wk = (const float*)d_in[5];
    const float* bk = (const float*)d_in[6];
    const float* Wv = (const float*)d_in[7];
    const float* bv = (const float*)d_in[8];
    const float* Wo = (const float*)d_in[9];
    const float* bo = (const float*)d_in[10];

    uint16_t* Qb = (uint16_t*)d_ws;          // bf16 [32768][512]
    uint16_t* KT = Qb + OUT0_ELEMS;          // bf16 [4][512][8192] keys^T
    uint16_t* VT = KT + OUT0_ELEMS;          // bf16 [4][512][8192] values^T
    uint16_t* Wb = VT + OUT0_ELEMS;          // 4 x [512][512] bf16
    uint16_t* KVf = VT;                      // VT dead after kv_kernel -> reuse
    uint16_t* Yb = KT;                       // KT dead after kv_kernel -> reuse

    float* out0 = (float*)d_out;
    float* kvz  = out0 + OUT0_ELEMS;         // kv (131072) then z (2048)

    hipMemsetAsync(kvz, 0, (KV_ELEMS + Z_ELEMS) * sizeof(float), stream);
    wconv_kernel<<<dim3(256, 4), 256, 0, stream>>>(Wq, Wk, Wv, Wo, Wb);
    gemm_kernel<true, true,  false, false><<<dim3(256, 4), 256, 0, stream>>>(q, Wb,              bq, Qb);
    gemm_kernel<true, true,  false, true ><<<dim3(256, 4), 256, 0, stream>>>(k, Wb + 262144,     bk, KT);
    gemm_kernel<true, false, false, true ><<<dim3(256, 4), 256, 0, stream>>>(v, Wb + 2 * 262144, bv, VT);
    kv_kernel<<<dim3(16, 32), 256, 0, stream>>>(KT, VT, kvz);
    kvf_kernel<<<dim3(32), 256, 0, stream>>>(kvz, KVf);
    attn_kernel<<<dim3(64, 32), 256, 0, stream>>>(Qb, KVf, Yb);
    gemm_kernel<false, false, true, false><<<dim3(256, 4), 256, 0, stream>>>(Yb, Wb + 3 * 262144, bo, out0);
}